// Round 11
// baseline (263.829 us; speedup 1.0000x reference)
//
#include <hip/hip_runtime.h>
#include <math.h>

#define B_   2
#define S_   2048
#define HID_ 1024
#define D_   64
#define H_   16
#define ROT_ 32
#define M_   (B_*S_)

typedef __attribute__((ext_vector_type(4))) short  short4v;
typedef __attribute__((ext_vector_type(8))) short  short8;
typedef __attribute__((ext_vector_type(4))) float  floatx4;
typedef __attribute__((ext_vector_type(16))) float floatx16;
typedef __attribute__((ext_vector_type(2))) unsigned int uint2v;

__device__ __forceinline__ unsigned short f2bf(float f) {
  unsigned int x = __builtin_bit_cast(unsigned int, f);
  x += 0x7fffu + ((x >> 16) & 1u);   // RNE; inputs finite
  return (unsigned short)(x >> 16);
}
__device__ __forceinline__ unsigned int cvt_pk_bf16(float lo, float hi) {
  unsigned int r;
  asm("v_cvt_pk_bf16_f32 %0, %1, %2" : "=v"(r) : "v"(lo), "v"(hi));
  return r;
}
// async global->LDS, 16B per lane; lds dest = wave-uniform base + lane*16
__device__ __forceinline__ void gload_lds16(const unsigned short* g, unsigned short* l) {
  __builtin_amdgcn_global_load_lds(
      (const __attribute__((address_space(1))) unsigned int*)g,
      (__attribute__((address_space(3))) unsigned int*)l, 16, 0, 0);
}

// ---------------- cast x (fp32 -> bf16) ----------------
__global__ void cast_bf16(const float* __restrict__ in, unsigned short* __restrict__ out) {
  int i = (blockIdx.x * 256 + threadIdx.x) * 4;
  floatx4 v = *(const floatx4*)(in + i);
  unsigned short o[4];
  o[0] = f2bf(v[0]); o[1] = f2bf(v[1]); o[2] = f2bf(v[2]); o[3] = f2bf(v[3]);
  *(unsigned long long*)(out + i) = *(unsigned long long*)o;
}

// ------------- transpose + cast weights: T[n][k] = bf16(W[k][n]) -------------
__global__ void transW(const float* __restrict__ W0, const float* __restrict__ W1,
                       const float* __restrict__ W2, const float* __restrict__ W3,
                       unsigned short* __restrict__ T0, unsigned short* __restrict__ T1,
                       unsigned short* __restrict__ T2, unsigned short* __restrict__ T3) {
  const float* W; unsigned short* T;
  int z = blockIdx.z;
  if (z == 0)      { W = W0; T = T0; }
  else if (z == 1) { W = W1; T = T1; }
  else if (z == 2) { W = W2; T = T2; }
  else             { W = W3; T = T3; }
  __shared__ float tile[32][33];
  int bx = blockIdx.x * 32, by = blockIdx.y * 32;
  int tx = threadIdx.x, ty = threadIdx.y;
  #pragma unroll
  for (int j = 0; j < 4; j++)
    tile[ty + j*8][tx] = W[(size_t)(by + ty + j*8) * HID_ + bx + tx];
  __syncthreads();
  #pragma unroll
  for (int j = 0; j < 4; j++)
    T[(size_t)(bx + ty + j*8) * HID_ + by + tx] = f2bf(tile[tx][ty + j*8]);
}

// ---------------- GEMM: C[M,N] = A[M,K] @ Bt[N,K]^T (+bias) ----------------
// R8 (T4): 3-buffer LDS, ONE raw s_barrier per K-step, counted vmcnt(4).
template <int MODE>
__global__ __launch_bounds__(256) void gemm_bt(
    const unsigned short* __restrict__ A,
    const unsigned short* __restrict__ Bt0, const unsigned short* __restrict__ Bt1,
    const unsigned short* __restrict__ Bt2,
    const float* __restrict__ bias0, const float* __restrict__ bias1,
    const float* __restrict__ bias2,
    void* __restrict__ out0, void* __restrict__ out1, void* __restrict__ out2,
    const float* __restrict__ sins, float sc0)
{
  const unsigned short* Bt; const float* bias; void* Out; float sc;
  if (blockIdx.z == 0)      { Bt = Bt0; bias = bias0; Out = out0; sc = sc0; }
  else if (blockIdx.z == 1) { Bt = Bt1; bias = bias1; Out = out1; sc = 1.f; }
  else                      { Bt = Bt2; bias = bias2; Out = out2; sc = 1.f; }
  const int K = HID_, N = HID_;
  int m0 = blockIdx.y * 128, n0 = blockIdx.x * 128;
  __shared__ alignas(16) unsigned short sA[3][128 * 32];
  __shared__ alignas(16) unsigned short sB[3][128 * 32];
  int t = threadIdx.x;
  int lane = t & 63, wave = t >> 6;
  int quad = lane >> 4, l16 = lane & 15;
  int wr = wave >> 1, wc = wave & 1;

  int srow = (lane >> 2), scol = (lane & 3) * 8;
  const unsigned short* gA0 = A  + (size_t)(m0 + wave*32 +  0 + srow) * K + scol;
  const unsigned short* gA1 = A  + (size_t)(m0 + wave*32 + 16 + srow) * K + scol;
  const unsigned short* gB0 = Bt + (size_t)(n0 + wave*32 +  0 + srow) * K + scol;
  const unsigned short* gB1 = Bt + (size_t)(n0 + wave*32 + 16 + srow) * K + scol;

#define GSTAGE(bi, k0) do { \
    gload_lds16(gA0 + (k0), sA[bi] + (wave*32 +  0) * 32); \
    gload_lds16(gA1 + (k0), sA[bi] + (wave*32 + 16) * 32); \
    gload_lds16(gB0 + (k0), sB[bi] + (wave*32 +  0) * 32); \
    gload_lds16(gB1 + (k0), sB[bi] + (wave*32 + 16) * 32); \
  } while (0)

  floatx4 acc[4][4];
  #pragma unroll
  for (int i = 0; i < 4; i++)
    #pragma unroll
    for (int j = 0; j < 4; j++)
      acc[i][j] = (floatx4){0.f, 0.f, 0.f, 0.f};

  const int NK = K / 32;
  GSTAGE(0, 0);
  GSTAGE(1, 32);
  for (int ks = 0; ks < NK; ks++) {
    int cur = ks % 3;
    if (ks + 1 < NK) asm volatile("s_waitcnt vmcnt(4)" ::: "memory");
    else             asm volatile("s_waitcnt vmcnt(0)" ::: "memory");
    __builtin_amdgcn_s_barrier();
    __builtin_amdgcn_sched_barrier(0);
    if (ks + 2 < NK) GSTAGE((ks + 2) % 3, (ks + 2) * 32);

    short8 af[4], bf[4];
    #pragma unroll
    for (int i = 0; i < 4; i++) {
      af[i] = *(const short8*)(sA[cur] + (wr * 64 + i * 16 + l16) * 32 + quad * 8);
      bf[i] = *(const short8*)(sB[cur] + (wc * 64 + i * 16 + l16) * 32 + quad * 8);
    }
    #pragma unroll
    for (int i = 0; i < 4; i++)
      #pragma unroll
      for (int j = 0; j < 4; j++)
        acc[i][j] = __builtin_amdgcn_mfma_f32_16x16x32_bf16(af[i], bf[j], acc[i][j], 0, 0, 0);
  }
#undef GSTAGE

  // Epilogue. C/D layout: col = lane&15, row = quad*4 + reg.
  #pragma unroll
  for (int i = 0; i < 4; i++) {
    int mbase = m0 + wr * 64 + i * 16 + quad * 4;
    #pragma unroll
    for (int j = 0; j < 4; j++) {
      int n = n0 + wc * 64 + j * 16 + l16;
      float bv = bias ? bias[n] : 0.f;
      if (MODE == 1) {
        #pragma unroll
        for (int r = 0; r < 4; r++)
          ((float*)Out)[(size_t)(mbase + r) * N + n] = acc[i][j][r] + bv;
      } else if (blockIdx.z == 2) {
        int bb = mbase >> 11, ss = mbase & 2047;
        int hh = n >> 6, dd = n & 63;
        unsigned short pk[4];
        #pragma unroll
        for (int r = 0; r < 4; r++) pk[r] = f2bf(acc[i][j][r] + bv);
        *(unsigned long long*)((unsigned short*)Out +
            (((size_t)(bb * H_ + hh) * D_ + dd) * S_ + ss)) = *(unsigned long long*)pk;
      } else if (j < 2) {
        int jh = j * 16 + l16;
        #pragma unroll
        for (int r = 0; r < 4; r++) {
          int row = mbase + r, bb = row >> 11, ss = row & 2047;
          float sn = sins[((size_t)(bb * 2 + 0) * S_ + ss) * ROT_ + jh];
          float cs = sins[((size_t)(bb * 2 + 1) * S_ + ss) * ROT_ + jh];
          float f = (jh & 1) ? (cs + sn) : (cs - sn);
          ((unsigned short*)Out)[(size_t)row * N + n] = f2bf((acc[i][j][r] + bv) * f * sc);
        }
      } else {
        #pragma unroll
        for (int r = 0; r < 4; r++)
          ((unsigned short*)Out)[(size_t)(mbase + r) * N + n] = f2bf((acc[i][j][r] + bv) * sc);
      }
    }
  }
}

// ---- final projection GEMM: 128(M)x64(N) tile, fp32 out, T4 3-buffer ----
__global__ __launch_bounds__(256) void gemm_bt64(
    const unsigned short* __restrict__ A, const unsigned short* __restrict__ Bt,
    float* __restrict__ Out)
{
  const int K = HID_, N = HID_;
  int m0 = blockIdx.y * 128, n0 = blockIdx.x * 64;
  __shared__ alignas(16) unsigned short sA[3][128 * 32];
  __shared__ alignas(16) unsigned short sB[3][64 * 32];
  int t = threadIdx.x;
  int lane = t & 63, wave = t >> 6;
  int quad = lane >> 4, l16 = lane & 15;
  int wr = wave >> 1, wc = wave & 1;

  int srow = lane >> 2, scol = (lane & 3) * 8;
  const unsigned short* gA0 = A  + (size_t)(m0 + wave*32 +  0 + srow) * K + scol;
  const unsigned short* gA1 = A  + (size_t)(m0 + wave*32 + 16 + srow) * K + scol;
  const unsigned short* gB0 = Bt + (size_t)(n0 + wave*16 + srow) * K + scol;

#define GSTAGE(bi, k0) do { \
    gload_lds16(gA0 + (k0), sA[bi] + (wave*32 +  0) * 32); \
    gload_lds16(gA1 + (k0), sA[bi] + (wave*32 + 16) * 32); \
    gload_lds16(gB0 + (k0), sB[bi] + (wave*16) * 32); \
  } while (0)

  floatx4 acc[4][2];
  #pragma unroll
  for (int i = 0; i < 4; i++)
    #pragma unroll
    for (int j = 0; j < 2; j++)
      acc[i][j] = (floatx4){0.f, 0.f, 0.f, 0.f};

  const int NK = K / 32;
  GSTAGE(0, 0);
  GSTAGE(1, 32);
  for (int ks = 0; ks < NK; ks++) {
    int cur = ks % 3;
    if (ks + 1 < NK) asm volatile("s_waitcnt vmcnt(3)" ::: "memory");
    else             asm volatile("s_waitcnt vmcnt(0)" ::: "memory");
    __builtin_amdgcn_s_barrier();
    __builtin_amdgcn_sched_barrier(0);
    if (ks + 2 < NK) GSTAGE((ks + 2) % 3, (ks + 2) * 32);

    short8 af[4], bf[2];
    #pragma unroll
    for (int i = 0; i < 4; i++)
      af[i] = *(const short8*)(sA[cur] + (wr * 64 + i * 16 + l16) * 32 + quad * 8);
    #pragma unroll
    for (int j = 0; j < 2; j++)
      bf[j] = *(const short8*)(sB[cur] + (wc * 32 + j * 16 + l16) * 32 + quad * 8);
    #pragma unroll
    for (int i = 0; i < 4; i++)
      #pragma unroll
      for (int j = 0; j < 2; j++)
        acc[i][j] = __builtin_amdgcn_mfma_f32_16x16x32_bf16(af[i], bf[j], acc[i][j], 0, 0, 0);
  }
#undef GSTAGE

  #pragma unroll
  for (int i = 0; i < 4; i++) {
    int mbase = m0 + wr * 64 + i * 16 + quad * 4;
    #pragma unroll
    for (int j = 0; j < 2; j++) {
      int n = n0 + wc * 32 + j * 16 + l16;
      #pragma unroll
      for (int r = 0; r < 4; r++)
        Out[(size_t)(mbase + r) * N + n] = acc[i][j][r];
    }
  }
}

// ---------------- flash attention: split-K + 2-HEAD FUSION ----------------
// R9/R10 resubmission (byte-identical; both prior runs died on infra:
// container failure, then GPU-capacity timeout — kernel never executed).
// attention_bias is HEAD-INDEPENDENT: fuse 2 heads per block -> 256 blocks
// (ONE round), each wave runs TWO independent QK->SM->PV chains per tile
// (2x ILP) and each bias load feeds both heads. LDS: 2 groups x 2 bufs x
// 2 heads x (K 8K + V 8K) = 128KB. Double-buffer, stage-issued-BEFORE-
// bias-refills so top-of-body wait = counted vmcnt(8) (stage(t+1)+refills
// stay in flight). Per-head math identical -> absmax must stay 0.01757812.
__global__ __launch_bounds__(512, 1) void attn(
    const unsigned short* __restrict__ Q, const unsigned short* __restrict__ Kb,
    const unsigned short* __restrict__ Vt, const float* __restrict__ bias,
    unsigned short* __restrict__ Out)
{
  int b = blockIdx.z, hp = blockIdx.y;
  int h0 = hp * 2;
  int t = threadIdx.x;
  int lane = t & 63, wave = t >> 6;
  int g = wave >> 2, wg = wave & 3;
  int l32 = lane & 31, hl = lane >> 5;
  int s7 = l32 & 7;
  int q0 = blockIdx.x * 128 + wg * 32;
  const int RS = H_ * D_;
  const int NT = S_ / 128;        // 16 tiles of 64 keys per k-half
  const int VH = D_ * S_;         // V head stride (shorts)

  // LDS: group g at g*32768 shorts; buf bi at bi*16384:
  //   K head H at H*4096 ; V head H at 8192 + H*4096
  __shared__ alignas(16) unsigned short smem[65536];   // 128 KB
  unsigned short* bg = smem + g * 32768;

  const unsigned short* Qbase = Q + ((size_t)(b * S_) * H_ + h0) * D_;
  const unsigned short* Kbase = Kb + ((size_t)(b * S_) * H_ + h0) * D_;
  const unsigned short* Vbase = Vt + ((size_t)(b * H_) + h0) * D_ * S_;

  // Q B-frags for both heads (n=q=lane&31, k=d=16s+8hl+j)
  short8 qf[2][4];
  #pragma unroll
  for (int H = 0; H < 2; H++) {
    const unsigned short* qp = Qbase + (size_t)(q0 + l32) * RS + H * D_ + 8 * hl;
    qf[H][0] = *(const short8*)(qp);
    qf[H][1] = *(const short8*)(qp + 16);
    qf[H][2] = *(const short8*)(qp + 32);
    qf[H][3] = *(const short8*)(qp + 48);
  }

  // staging: thread tg covers 16B chunk of row (tg>>3) and row+32; src pre-swizzled
  int tg = t & 255;
  int row0 = tg >> 3;
  int csw  = (tg & 7) ^ (row0 & 7);
  const unsigned short* gK0 = Kbase + (size_t)(g*1024 + row0)      * RS + csw * 8;
  const unsigned short* gK1 = Kbase + (size_t)(g*1024 + row0 + 32) * RS + csw * 8;
  const unsigned short* gV0 = Vbase + (size_t)(row0)      * S_ + g*1024 + csw * 8;
  const unsigned short* gV1 = Vbase + (size_t)(row0 + 32) * S_ + g*1024 + csw * 8;

  const float* bp = bias + (size_t)b * S_ * S_ + (size_t)(q0 + l32) * S_ + g * 1024 + 4 * hl;

  // 8 loads per STAGE: K(h0)x2, K(h1)x2 (head1 = +64 shorts), V(h0)x2, V(h1)x2 (+VH)
#define STAGE(bi, tk) do { \
    unsigned short* base_ = bg + (bi) * 16384; \
    size_t ko_ = (size_t)(tk) * 64 * RS; int vo_ = (tk) * 64; \
    gload_lds16(gK0 + ko_,        base_ + tg * 8); \
    gload_lds16(gK1 + ko_,        base_ + (256 + tg) * 8); \
    gload_lds16(gK0 + ko_ + 64,   base_ + 4096 + tg * 8); \
    gload_lds16(gK1 + ko_ + 64,   base_ + 4096 + (256 + tg) * 8); \
    gload_lds16(gV0 + vo_,        base_ + 8192 + tg * 8); \
    gload_lds16(gV1 + vo_,        base_ + 8192 + (256 + tg) * 8); \
    gload_lds16(gV0 + vo_ + VH,   base_ + 12288 + tg * 8); \
    gload_lds16(gV1 + vo_ + VH,   base_ + 12288 + (256 + tg) * 8); \
  } while (0)

  float lr0 = 0.f, lr1 = 0.f;
  floatx16 o00, o01, o10, o11;   // o<head><dblk>
  #pragma unroll
  for (int r = 0; r < 16; r++) { o00[r] = 0.f; o01[r] = 0.f; o10[r] = 0.f; o11[r] = 0.f; }

  // prologue: STAGE(0) 8, bias(0) 8
  STAGE(0, 0);
  floatx4 b0[4], b1[4];
  #pragma unroll
  for (int rg = 0; rg < 4; rg++) {
    b0[rg] = *(const floatx4*)(bp + 8 * rg);
    b1[rg] = *(const floatx4*)(bp + 32 + 8 * rg);
  }

  for (int it = 0; it < NT; ++it) {
    int cur = it & 1;
    // outstanding at top: STAGE(it)(8, oldest) + bias refills (8 newer)
    asm volatile("s_waitcnt vmcnt(8)" ::: "memory");
    __builtin_amdgcn_s_barrier();
    __builtin_amdgcn_sched_barrier(0);
    if (it < NT - 1) STAGE(cur ^ 1, it + 1);   // buf cur^1 readers done (tile it-1)
    __builtin_amdgcn_sched_barrier(0);

    int itn = ((it + 1) & (NT - 1)) * 64;

    #pragma unroll
    for (int H = 0; H < 2; H++) {
      const unsigned short* kbuf = bg + cur * 16384 + H * 4096;
      const unsigned short* vbuf = bg + cur * 16384 + 8192 + H * 4096;
      floatx16& oa = H ? o10 : o00;
      floatx16& ob = H ? o11 : o01;
      float& lr = H ? lr1 : lr0;

      // ---- QK^T half 0: S^T rows k=0..31 ----
      floatx16 st;
      #pragma unroll
      for (int r = 0; r < 16; r++) st[r] = 0.f;
      __builtin_amdgcn_s_setprio(1);
      #pragma unroll
      for (int ks = 0; ks < 4; ks++) {
        short8 kf = *(const short8*)(kbuf + l32 * 64 + (((2 * ks + hl) ^ s7) * 8));
        st = __builtin_amdgcn_mfma_f32_32x32x16_bf16(kf, qf[H][ks], st, 0, 0, 0);
      }
      __builtin_amdgcn_s_setprio(0);

      // ---- softmax half 0 -> pf0 (uses b0) ----
      short4v pf0[4];
      #pragma unroll
      for (int rg = 0; rg < 4; rg++) {
        float p0 = __builtin_amdgcn_exp2f(st[rg * 4 + 0]);
        float p1 = __builtin_amdgcn_exp2f(st[rg * 4 + 1]);
        float p2 = __builtin_amdgcn_exp2f(st[rg * 4 + 2]);
        float p3 = __builtin_amdgcn_exp2f(st[rg * 4 + 3]);
        lr += (p0 + p1) + (p2 + p3);
        uint2v u;
        u[0] = cvt_pk_bf16(p0 * b0[rg][0], p1 * b0[rg][1]);
        u[1] = cvt_pk_bf16(p2 * b0[rg][2], p3 * b0[rg][3]);
        pf0[rg] = __builtin_bit_cast(short4v, u);
      }
      if (H == 1) {   // b0's last use done -> refill for next tile
        #pragma unroll
        for (int rg = 0; rg < 4; rg++)
          b0[rg] = *(const floatx4*)(bp + itn + 8 * rg);
      }

      // ---- QK^T half 1 ----
      floatx16 st1;
      #pragma unroll
      for (int r = 0; r < 16; r++) st1[r] = 0.f;
      __builtin_amdgcn_s_setprio(1);
      #pragma unroll
      for (int ks = 0; ks < 4; ks++) {
        short8 kf = *(const short8*)(kbuf + (32 + l32) * 64 + (((2 * ks + hl) ^ s7) * 8));
        st1 = __builtin_amdgcn_mfma_f32_32x32x16_bf16(kf, qf[H][ks], st1, 0, 0, 0);
      }
      // ---- PV half 0 ----
      #pragma unroll
      for (int gg = 0; gg < 4; gg++) {
        int ch = (gg ^ s7) * 8 + hl * 4;
        short4v vf0 = *(const short4v*)(vbuf + l32 * 64 + ch);
        short4v vf1 = *(const short4v*)(vbuf + (32 + l32) * 64 + ch);
        oa = __builtin_amdgcn_mfma_f32_32x32x8bf16_1k(pf0[gg], vf0, oa, 0, 0, 0);
        ob = __builtin_amdgcn_mfma_f32_32x32x8bf16_1k(pf0[gg], vf1, ob, 0, 0, 0);
      }
      __builtin_amdgcn_s_setprio(0);

      // ---- softmax half 1 -> pf1 (uses b1) ----
      short4v pf1[4];
      #pragma unroll
      for (int rg = 0; rg < 4; rg++) {
        float p0 = __builtin_amdgcn_exp2f(st1[rg * 4 + 0]);
        float p1 = __builtin_amdgcn_exp2f(st1[rg * 4 + 1]);
        float p2 = __builtin_amdgcn_exp2f(st1[rg * 4 + 2]);
        float p3 = __builtin_amdgcn_exp2f(st1[rg * 4 + 3]);
        lr += (p0 + p1) + (p2 + p3);
        uint2v u;
        u[0] = cvt_pk_bf16(p0 * b1[rg][0], p1 * b1[rg][1]);
        u[1] = cvt_pk_bf16(p2 * b1[rg][2], p3 * b1[rg][3]);
        pf1[rg] = __builtin_bit_cast(short4v, u);
      }
      if (H == 1) {
        #pragma unroll
        for (int rg = 0; rg < 4; rg++)
          b1[rg] = *(const floatx4*)(bp + itn + 32 + 8 * rg);
      }

      // ---- PV half 1 ----
      __builtin_amdgcn_s_setprio(1);
      #pragma unroll
      for (int gg = 0; gg < 4; gg++) {
        int ch = ((4 + gg) ^ s7) * 8 + hl * 4;
        short4v vf0 = *(const short4v*)(vbuf + l32 * 64 + ch);
        short4v vf1 = *(const short4v*)(vbuf + (32 + l32) * 64 + ch);
        oa = __builtin_amdgcn_mfma_f32_32x32x8bf16_1k(pf1[gg], vf0, oa, 0, 0, 0);
        ob = __builtin_amdgcn_mfma_f32_32x32x8bf16_1k(pf1[gg], vf1, ob, 0, 0, 0);
      }
      __builtin_amdgcn_s_setprio(0);
    }
  }
#undef STAGE

  // combine the two k-halves per head through LDS (K/V buffers dead)
  float* sO = (float*)smem;              // 128 q x 64 d fp32 = 32 KB
  float* sL = (float*)(smem + 16384);    // 128 floats

  #pragma unroll
  for (int H = 0; H < 2; H++) {
    floatx16& oa = H ? o10 : o00;
    floatx16& ob = H ? o11 : o01;
    float l2 = (H ? lr1 : lr0) + __shfl_xor(H ? lr1 : lr0, 32);

    __syncthreads();                     // also guards sO reuse between heads
    if (g == 1) {
      #pragma unroll
      for (int r = 0; r < 16; r++) {
        int ql = (r & 3) + 8 * (r >> 2) + 4 * hl;
        sO[(wg * 32 + ql) * 64 + l32]      = oa[r];
        sO[(wg * 32 + ql) * 64 + 32 + l32] = ob[r];
      }
      if (hl == 0) sL[wg * 32 + l32] = l2;
    }
    __syncthreads();
    if (g == 0) {
      float linv = __builtin_amdgcn_rcpf(l2 + sL[wg * 32 + l32]);
      #pragma unroll
      for (int r = 0; r < 16; r++) {
        int ql = (r & 3) + 8 * (r >> 2) + 4 * hl;
        float sc = __shfl(linv, ql);
        size_t base = ((size_t)(b * S_ + q0 + ql) * H_ + h0 + H) * D_;
        float a0 = oa[r] + sO[(wg * 32 + ql) * 64 + l32];
        float a1 = ob[r] + sO[(wg * 32 + ql) * 64 + 32 + l32];
        Out[base + l32]      = f2bf(a0 * sc);
        Out[base + 32 + l32] = f2bf(a1 * sc);
      }
    }
  }
}

// ---------------- launch ----------------
extern "C" void kernel_launch(void* const* d_in, const int* in_sizes, int n_in,
                              void* d_out, int out_size, void* d_ws, size_t ws_size,
                              hipStream_t stream) {
  (void)in_sizes; (void)n_in; (void)out_size; (void)ws_size;
  const float* x    = (const float*)d_in[0];
  const float* sins = (const float*)d_in[1];
  const float* ab   = (const float*)d_in[2];
  const float* Wq   = (const float*)d_in[3];
  const float* bq   = (const float*)d_in[4];
  const float* Wk   = (const float*)d_in[5];
  const float* bk   = (const float*)d_in[6];
  const float* Wv   = (const float*)d_in[7];
  const float* bv   = (const float*)d_in[8];
  const float* Wo   = (const float*)d_in[9];
  float* out = (float*)d_out;
  char* ws = (char*)d_ws;

  unsigned short* xb  = (unsigned short*)(ws);                       // 8 MB
  unsigned short* Wqt = (unsigned short*)(ws + ((size_t) 8 << 20));  // 2 MB each
  unsigned short* Wkt = (unsigned short*)(ws + ((size_t)10 << 20));
  unsigned short* Wvt = (unsigned short*)(ws + ((size_t)12 << 20));
  unsigned short* Wot = (unsigned short*)(ws + ((size_t)14 << 20));
  unsigned short* Qb  = (unsigned short*)(ws + ((size_t)16 << 20));  // 8 MB
  unsigned short* Kb  = (unsigned short*)(ws + ((size_t)24 << 20));  // 8 MB
  unsigned short* Vtb = (unsigned short*)(ws + ((size_t)32 << 20));  // 8 MB, [b][h][d][s]
  unsigned short* Ab  = (unsigned short*)(ws + ((size_t)40 << 20));  // 8 MB

  const float c1 = 0.125f * 1.44269504088896f;  // 1/sqrt(D) * log2(e), folded into Q

  cast_bf16<<<dim3((M_ * HID_) / (256 * 4)), dim3(256), 0, stream>>>(x, xb);
  transW<<<dim3(32, 32, 4), dim3(32, 8), 0, stream>>>(Wq, Wk, Wv, Wo, Wqt, Wkt, Wvt, Wot);
  gemm_bt<0><<<dim3(8, 32, 3), dim3(256), 0, stream>>>(xb, Wqt, Wkt, Wvt, bq, bk, bv,
                                                       Qb, Kb, Vtb, sins, c1);
  attn<<<dim3(S_ / 128, H_ / 2, B_), dim3(512), 0, stream>>>(Qb, Kb, Vtb, ab, Ab);
  gemm_bt64<<<dim3(HID_ / 64, M_ / 128), dim3(256), 0, stream>>>(Ab, Wot, out);
}

// Round 14
// 257.415 us; speedup vs baseline: 1.0249x; 1.0249x over previous
//
#include <hip/hip_runtime.h>
#include <math.h>

#define B_   2
#define S_   2048
#define HID_ 1024
#define D_   64
#define H_   16
#define ROT_ 32
#define M_   (B_*S_)

typedef __attribute__((ext_vector_type(4))) short  short4v;
typedef __attribute__((ext_vector_type(8))) short  short8;
typedef __attribute__((ext_vector_type(4))) float  floatx4;
typedef __attribute__((ext_vector_type(16))) float floatx16;
typedef __attribute__((ext_vector_type(2))) unsigned int uint2v;

__device__ __forceinline__ unsigned short f2bf(float f) {
  unsigned int x = __builtin_bit_cast(unsigned int, f);
  x += 0x7fffu + ((x >> 16) & 1u);   // RNE; inputs finite
  return (unsigned short)(x >> 16);
}
__device__ __forceinline__ unsigned int cvt_pk_bf16(float lo, float hi) {
  unsigned int r;
  asm("v_cvt_pk_bf16_f32 %0, %1, %2" : "=v"(r) : "v"(lo), "v"(hi));
  return r;
}
// async global->LDS, 16B per lane; lds dest = wave-uniform base + lane*16
__device__ __forceinline__ void gload_lds16(const unsigned short* g, unsigned short* l) {
  __builtin_amdgcn_global_load_lds(
      (const __attribute__((address_space(1))) unsigned int*)g,
      (__attribute__((address_space(3))) unsigned int*)l, 16, 0, 0);
}

// ---------------- cast x (fp32 -> bf16) ----------------
__global__ void cast_bf16(const float* __restrict__ in, unsigned short* __restrict__ out) {
  int i = (blockIdx.x * 256 + threadIdx.x) * 4;
  floatx4 v = *(const floatx4*)(in + i);
  unsigned short o[4];
  o[0] = f2bf(v[0]); o[1] = f2bf(v[1]); o[2] = f2bf(v[2]); o[3] = f2bf(v[3]);
  *(unsigned long long*)(out + i) = *(unsigned long long*)o;
}

// ------------- transpose + cast weights: T[n][k] = bf16(W[k][n]) -------------
__global__ void transW(const float* __restrict__ W0, const float* __restrict__ W1,
                       const float* __restrict__ W2, const float* __restrict__ W3,
                       unsigned short* __restrict__ T0, unsigned short* __restrict__ T1,
                       unsigned short* __restrict__ T2, unsigned short* __restrict__ T3) {
  const float* W; unsigned short* T;
  int z = blockIdx.z;
  if (z == 0)      { W = W0; T = T0; }
  else if (z == 1) { W = W1; T = T1; }
  else if (z == 2) { W = W2; T = T2; }
  else             { W = W3; T = T3; }
  __shared__ float tile[32][33];
  int bx = blockIdx.x * 32, by = blockIdx.y * 32;
  int tx = threadIdx.x, ty = threadIdx.y;
  #pragma unroll
  for (int j = 0; j < 4; j++)
    tile[ty + j*8][tx] = W[(size_t)(by + ty + j*8) * HID_ + bx + tx];
  __syncthreads();
  #pragma unroll
  for (int j = 0; j < 4; j++)
    T[(size_t)(bx + ty + j*8) * HID_ + by + tx] = f2bf(tile[tx][ty + j*8]);
}

// ---------------- GEMM: C[M,N] = A[M,K] @ Bt[N,K]^T (+bias) ----------------
// R8 (T4): 3-buffer LDS, ONE raw s_barrier per K-step, counted vmcnt(4).
// R12 (T1-chunked): the 8 blocks sharing an A-tile were round-robined onto 8
// different XCDs -> A-tile fetched 8x from L3. Reverse-chunked swizzle
// work = (wg&7)*96 + wg>>3 gives each XCD a contiguous work range, so
// A-sharing blocks co-locate on one XCD's L2. 768%8==0 -> bijective.
template <int MODE>
__global__ __launch_bounds__(256) void gemm_bt(
    const unsigned short* __restrict__ A,
    const unsigned short* __restrict__ Bt0, const unsigned short* __restrict__ Bt1,
    const unsigned short* __restrict__ Bt2,
    const float* __restrict__ bias0, const float* __restrict__ bias1,
    const float* __restrict__ bias2,
    void* __restrict__ out0, void* __restrict__ out1, void* __restrict__ out2,
    const float* __restrict__ sins, float sc0)
{
  // XCD-chunked remap of the 768-block grid (x=8 n-tiles, y=32 m-tiles, z=3)
  int wg = blockIdx.x + (blockIdx.y << 3) + (blockIdx.z << 8);
  int work = (wg & 7) * 96 + (wg >> 3);
  int zz = work >> 8;
  int rem = work & 255;
  int ty_ = rem >> 3, tx_ = rem & 7;

  const unsigned short* Bt; const float* bias; void* Out; float sc;
  if (zz == 0)      { Bt = Bt0; bias = bias0; Out = out0; sc = sc0; }
  else if (zz == 1) { Bt = Bt1; bias = bias1; Out = out1; sc = 1.f; }
  else              { Bt = Bt2; bias = bias2; Out = out2; sc = 1.f; }
  const int K = HID_, N = HID_;
  int m0 = ty_ * 128, n0 = tx_ * 128;
  __shared__ alignas(16) unsigned short sA[3][128 * 32];
  __shared__ alignas(16) unsigned short sB[3][128 * 32];
  int t = threadIdx.x;
  int lane = t & 63, wave = t >> 6;
  int quad = lane >> 4, l16 = lane & 15;
  int wr = wave >> 1, wc = wave & 1;

  int srow = (lane >> 2), scol = (lane & 3) * 8;
  const unsigned short* gA0 = A  + (size_t)(m0 + wave*32 +  0 + srow) * K + scol;
  const unsigned short* gA1 = A  + (size_t)(m0 + wave*32 + 16 + srow) * K + scol;
  const unsigned short* gB0 = Bt + (size_t)(n0 + wave*32 +  0 + srow) * K + scol;
  const unsigned short* gB1 = Bt + (size_t)(n0 + wave*32 + 16 + srow) * K + scol;

#define GSTAGE(bi, k0) do { \
    gload_lds16(gA0 + (k0), sA[bi] + (wave*32 +  0) * 32); \
    gload_lds16(gA1 + (k0), sA[bi] + (wave*32 + 16) * 32); \
    gload_lds16(gB0 + (k0), sB[bi] + (wave*32 +  0) * 32); \
    gload_lds16(gB1 + (k0), sB[bi] + (wave*32 + 16) * 32); \
  } while (0)

  floatx4 acc[4][4];
  #pragma unroll
  for (int i = 0; i < 4; i++)
    #pragma unroll
    for (int j = 0; j < 4; j++)
      acc[i][j] = (floatx4){0.f, 0.f, 0.f, 0.f};

  const int NK = K / 32;
  GSTAGE(0, 0);
  GSTAGE(1, 32);
  for (int ks = 0; ks < NK; ks++) {
    int cur = ks % 3;
    if (ks + 1 < NK) asm volatile("s_waitcnt vmcnt(4)" ::: "memory");
    else             asm volatile("s_waitcnt vmcnt(0)" ::: "memory");
    __builtin_amdgcn_s_barrier();
    __builtin_amdgcn_sched_barrier(0);
    if (ks + 2 < NK) GSTAGE((ks + 2) % 3, (ks + 2) * 32);

    short8 af[4], bf[4];
    #pragma unroll
    for (int i = 0; i < 4; i++) {
      af[i] = *(const short8*)(sA[cur] + (wr * 64 + i * 16 + l16) * 32 + quad * 8);
      bf[i] = *(const short8*)(sB[cur] + (wc * 64 + i * 16 + l16) * 32 + quad * 8);
    }
    #pragma unroll
    for (int i = 0; i < 4; i++)
      #pragma unroll
      for (int j = 0; j < 4; j++)
        acc[i][j] = __builtin_amdgcn_mfma_f32_16x16x32_bf16(af[i], bf[j], acc[i][j], 0, 0, 0);
  }
#undef GSTAGE

  // Epilogue. C/D layout: col = lane&15, row = quad*4 + reg.
  #pragma unroll
  for (int i = 0; i < 4; i++) {
    int mbase = m0 + wr * 64 + i * 16 + quad * 4;
    #pragma unroll
    for (int j = 0; j < 4; j++) {
      int n = n0 + wc * 64 + j * 16 + l16;
      float bv = bias ? bias[n] : 0.f;
      if (MODE == 1) {
        #pragma unroll
        for (int r = 0; r < 4; r++)
          ((float*)Out)[(size_t)(mbase + r) * N + n] = acc[i][j][r] + bv;
      } else if (zz == 2) {
        // V: write transposed Vt[((b*16+h)*64+dd)*2048 + s], 4 consecutive s packed
        int bb = mbase >> 11, ss = mbase & 2047;
        int hh = n >> 6, dd = n & 63;
        unsigned short pk[4];
        #pragma unroll
        for (int r = 0; r < 4; r++) pk[r] = f2bf(acc[i][j][r] + bv);
        *(unsigned long long*)((unsigned short*)Out +
            (((size_t)(bb * H_ + hh) * D_ + dd) * S_ + ss)) = *(unsigned long long*)pk;
      } else if (j < 2) {
        // rope columns: head-dim index jh = j*16 + l16 < 32 (wave-uniform branch)
        int jh = j * 16 + l16;
        #pragma unroll
        for (int r = 0; r < 4; r++) {
          int row = mbase + r, bb = row >> 11, ss = row & 2047;
          float sn = sins[((size_t)(bb * 2 + 0) * S_ + ss) * ROT_ + jh];
          float cs = sins[((size_t)(bb * 2 + 1) * S_ + ss) * ROT_ + jh];
          float f = (jh & 1) ? (cs + sn) : (cs - sn);
          ((unsigned short*)Out)[(size_t)row * N + n] = f2bf((acc[i][j][r] + bv) * f * sc);
        }
      } else {
        #pragma unroll
        for (int r = 0; r < 4; r++)
          ((unsigned short*)Out)[(size_t)(mbase + r) * N + n] = f2bf((acc[i][j][r] + bv) * sc);
      }
    }
  }
}

// ---- final projection GEMM: 128(M)x64(N) tile, fp32 out, T4 3-buffer ----
// R12: same XCD-chunked swizzle (512 blocks, chunk=64; 16 x-tiles share A).
__global__ __launch_bounds__(256) void gemm_bt64(
    const unsigned short* __restrict__ A, const unsigned short* __restrict__ Bt,
    float* __restrict__ Out)
{
  const int K = HID_, N = HID_;
  int wg = blockIdx.x + (blockIdx.y << 4);       // x=16 n-tiles, y=32 m-tiles
  int work = (wg & 7) * 64 + (wg >> 3);
  int m0 = (work >> 4) * 128, n0 = (work & 15) * 64;
  __shared__ alignas(16) unsigned short sA[3][128 * 32];
  __shared__ alignas(16) unsigned short sB[3][64 * 32];
  int t = threadIdx.x;
  int lane = t & 63, wave = t >> 6;
  int quad = lane >> 4, l16 = lane & 15;
  int wr = wave >> 1, wc = wave & 1;

  int srow = lane >> 2, scol = (lane & 3) * 8;
  const unsigned short* gA0 = A  + (size_t)(m0 + wave*32 +  0 + srow) * K + scol;
  const unsigned short* gA1 = A  + (size_t)(m0 + wave*32 + 16 + srow) * K + scol;
  const unsigned short* gB0 = Bt + (size_t)(n0 + wave*16 + srow) * K + scol;

#define GSTAGE(bi, k0) do { \
    gload_lds16(gA0 + (k0), sA[bi] + (wave*32 +  0) * 32); \
    gload_lds16(gA1 + (k0), sA[bi] + (wave*32 + 16) * 32); \
    gload_lds16(gB0 + (k0), sB[bi] + (wave*16) * 32); \
  } while (0)

  floatx4 acc[4][2];
  #pragma unroll
  for (int i = 0; i < 4; i++)
    #pragma unroll
    for (int j = 0; j < 2; j++)
      acc[i][j] = (floatx4){0.f, 0.f, 0.f, 0.f};

  const int NK = K / 32;
  GSTAGE(0, 0);
  GSTAGE(1, 32);
  for (int ks = 0; ks < NK; ks++) {
    int cur = ks % 3;
    if (ks + 1 < NK) asm volatile("s_waitcnt vmcnt(3)" ::: "memory");
    else             asm volatile("s_waitcnt vmcnt(0)" ::: "memory");
    __builtin_amdgcn_s_barrier();
    __builtin_amdgcn_sched_barrier(0);
    if (ks + 2 < NK) GSTAGE((ks + 2) % 3, (ks + 2) * 32);

    short8 af[4], bf[2];
    #pragma unroll
    for (int i = 0; i < 4; i++)
      af[i] = *(const short8*)(sA[cur] + (wr * 64 + i * 16 + l16) * 32 + quad * 8);
    #pragma unroll
    for (int j = 0; j < 2; j++)
      bf[j] = *(const short8*)(sB[cur] + (wc * 32 + j * 16 + l16) * 32 + quad * 8);
    #pragma unroll
    for (int i = 0; i < 4; i++)
      #pragma unroll
      for (int j = 0; j < 2; j++)
        acc[i][j] = __builtin_amdgcn_mfma_f32_16x16x32_bf16(af[i], bf[j], acc[i][j], 0, 0, 0);
  }
#undef GSTAGE

  #pragma unroll
  for (int i = 0; i < 4; i++) {
    int mbase = m0 + wr * 64 + i * 16 + quad * 4;
    #pragma unroll
    for (int j = 0; j < 2; j++) {
      int n = n0 + wc * 32 + j * 16 + l16;
      #pragma unroll
      for (int r = 0; r < 4; r++)
        Out[(size_t)(mbase + r) * N + n] = acc[i][j][r];
    }
  }
}

// ---------------- flash attention (FROZEN at R8 best: 98.6us) ----------------
// R11 post-mortem: 2-head fusion hit the register wall (VGPR 128, +11MB spill
// traffic) and landed at 103us — per the pre-committed rule, attn is floored
// at ~98us (serialized per-tile chain); frozen at the R8 single-head version.
__global__ __launch_bounds__(512, 1) void attn(
    const unsigned short* __restrict__ Q, const unsigned short* __restrict__ Kb,
    const unsigned short* __restrict__ Vt, const float* __restrict__ bias,
    unsigned short* __restrict__ Out)
{
  int b = blockIdx.z, h = blockIdx.y;
  int t = threadIdx.x;
  int lane = t & 63, wave = t >> 6;
  int g = wave >> 2, wg = wave & 3;
  int l32 = lane & 31, hl = lane >> 5;
  int s7 = l32 & 7;
  int q0 = blockIdx.x * 128 + wg * 32;
  const int RS = H_ * D_;
  const int NT = S_ / 128;   // 16 tiles of 64 keys per k-half

  // LDS (shorts), per group 32768: K buf[i] at i*4096, V buf[i] at 16384+i*4096
  __shared__ alignas(16) unsigned short smem[65536];   // 128 KB
  unsigned short* bg = smem + g * 32768;

  const unsigned short* Qbase = Q + ((size_t)(b * S_) * H_ + h) * D_;
  const unsigned short* Kbase = Kb + ((size_t)(b * S_) * H_ + h) * D_;
  const unsigned short* Vbase = Vt + ((size_t)(b * H_) + h) * D_ * S_;

  // Q B-frags (n=q=lane&31, k=d=16s+8hl+j), fixed for whole kernel
  short8 qf[4];
  {
    const unsigned short* qp = Qbase + (size_t)(q0 + l32) * RS + 8 * hl;
    qf[0] = *(const short8*)(qp);
    qf[1] = *(const short8*)(qp + 16);
    qf[2] = *(const short8*)(qp + 32);
    qf[3] = *(const short8*)(qp + 48);
  }

  // staging geometry: group-local thread tg covers 16B chunk d=tg (rows 0..31)
  // and d=256+tg (rows 32..63); 8 chunks per 128B row; source chunk pre-swizzled.
  int tg = t & 255;
  int row0 = tg >> 3;                  // 0..31
  int csw  = (tg & 7) ^ (row0 & 7);    // swizzled source chunk (row&7 same for row0+32)
  const unsigned short* gK0 = Kbase + (size_t)(g*1024 + row0)      * RS + csw * 8;
  const unsigned short* gK1 = Kbase + (size_t)(g*1024 + row0 + 32) * RS + csw * 8;
  const unsigned short* gV0 = Vbase + (size_t)(row0)      * S_ + g*1024 + csw * 8;
  const unsigned short* gV1 = Vbase + (size_t)(row0 + 32) * S_ + g*1024 + csw * 8;

  const float* bp = bias + (size_t)b * S_ * S_ + (size_t)(q0 + l32) * S_ + g * 1024 + 4 * hl;

#define STAGE(bi, tk) do { \
    unsigned short* kb_ = bg + (bi) * 4096; \
    unsigned short* vb_ = bg + 16384 + (bi) * 4096; \
    size_t ko_ = (size_t)(tk) * 64 * RS; int vo_ = (tk) * 64; \
    gload_lds16(gK0 + ko_, kb_ + tg * 8); \
    gload_lds16(gK1 + ko_, kb_ + (256 + tg) * 8); \
    gload_lds16(gV0 + vo_, vb_ + tg * 8); \
    gload_lds16(gV1 + vo_, vb_ + (256 + tg) * 8); \
  } while (0)

  float l_run = 0.f;
  floatx16 o0, o1;
  #pragma unroll
  for (int r = 0; r < 16; r++) { o0[r] = 0.f; o1[r] = 0.f; }

  // prologue (VMEM order matters for the counted waits):
  // stage(0) 4, bias(0) 8, stage(1) 4, stage(2) 4  -> 20 in flight
  STAGE(0, 0);
  floatx4 b0[4], b1[4];
  #pragma unroll
  for (int rg = 0; rg < 4; rg++) {
    b0[rg] = *(const floatx4*)(bp + 8 * rg);
    b1[rg] = *(const floatx4*)(bp + 32 + 8 * rg);
  }
  STAGE(1, 1);
  STAGE(2, 2);

  for (int it = 0; it < NT; ++it) {
    int cur = it & 3;
    // counted wait: stage(cur) complete, newer stages + bias stay in flight
    asm volatile("s_waitcnt vmcnt(16)" ::: "memory");
    __builtin_amdgcn_s_barrier();
    __builtin_amdgcn_sched_barrier(0);
    if (it < NT - 3) STAGE((it + 3) & 3, it + 3);

    const unsigned short* kbuf = bg + cur * 4096;
    const unsigned short* vbuf = bg + 16384 + cur * 4096;
    int itn = ((it + 1) & (NT - 1)) * 64;

    // ---- QK^T half 0: S^T rows k=0..31 (D[m=k][n=q]) ----
    floatx16 st;
    #pragma unroll
    for (int r = 0; r < 16; r++) st[r] = 0.f;
    __builtin_amdgcn_s_setprio(1);
    #pragma unroll
    for (int ks = 0; ks < 4; ks++) {
      short8 kf = *(const short8*)(kbuf + l32 * 64 + (((2 * ks + hl) ^ s7) * 8));
      st = __builtin_amdgcn_mfma_f32_32x32x16_bf16(kf, qf[ks], st, 0, 0, 0);
    }
    __builtin_amdgcn_s_setprio(0);

    // ---- softmax half 0 -> pf0; refill b0 for next tile ----
    short4v pf0[4];
    #pragma unroll
    for (int rg = 0; rg < 4; rg++) {
      float p0 = __builtin_amdgcn_exp2f(st[rg * 4 + 0]);
      float p1 = __builtin_amdgcn_exp2f(st[rg * 4 + 1]);
      float p2 = __builtin_amdgcn_exp2f(st[rg * 4 + 2]);
      float p3 = __builtin_amdgcn_exp2f(st[rg * 4 + 3]);
      l_run += (p0 + p1) + (p2 + p3);
      uint2v u;
      u[0] = cvt_pk_bf16(p0 * b0[rg][0], p1 * b0[rg][1]);
      u[1] = cvt_pk_bf16(p2 * b0[rg][2], p3 * b0[rg][3]);
      pf0[rg] = __builtin_bit_cast(short4v, u);
    }
    #pragma unroll
    for (int rg = 0; rg < 4; rg++)
      b0[rg] = *(const floatx4*)(bp + itn + 8 * rg);

    // ---- QK^T half 1 (st registers recycled) ----
    floatx16 st1;
    #pragma unroll
    for (int r = 0; r < 16; r++) st1[r] = 0.f;
    __builtin_amdgcn_s_setprio(1);
    #pragma unroll
    for (int ks = 0; ks < 4; ks++) {
      short8 kf = *(const short8*)(kbuf + (32 + l32) * 64 + (((2 * ks + hl) ^ s7) * 8));
      st1 = __builtin_amdgcn_mfma_f32_32x32x16_bf16(kf, qf[ks], st1, 0, 0, 0);
    }
    // ---- PV half 0 ----
    #pragma unroll
    for (int gg = 0; gg < 4; gg++) {
      int ch = (gg ^ s7) * 8 + hl * 4;
      short4v vf0 = *(const short4v*)(vbuf + l32 * 64 + ch);
      short4v vf1 = *(const short4v*)(vbuf + (32 + l32) * 64 + ch);
      o0 = __builtin_amdgcn_mfma_f32_32x32x8bf16_1k(pf0[gg], vf0, o0, 0, 0, 0);
      o1 = __builtin_amdgcn_mfma_f32_32x32x8bf16_1k(pf0[gg], vf1, o1, 0, 0, 0);
    }
    __builtin_amdgcn_s_setprio(0);

    // ---- softmax half 1 -> pf1; refill b1 ----
    short4v pf1[4];
    #pragma unroll
    for (int rg = 0; rg < 4; rg++) {
      float p0 = __builtin_amdgcn_exp2f(st1[rg * 4 + 0]);
      float p1 = __builtin_amdgcn_exp2f(st1[rg * 4 + 1]);
      float p2 = __builtin_amdgcn_exp2f(st1[rg * 4 + 2]);
      float p3 = __builtin_amdgcn_exp2f(st1[rg * 4 + 3]);
      l_run += (p0 + p1) + (p2 + p3);
      uint2v u;
      u[0] = cvt_pk_bf16(p0 * b1[rg][0], p1 * b1[rg][1]);
      u[1] = cvt_pk_bf16(p2 * b1[rg][2], p3 * b1[rg][3]);
      pf1[rg] = __builtin_bit_cast(short4v, u);
    }
    #pragma unroll
    for (int rg = 0; rg < 4; rg++)
      b1[rg] = *(const floatx4*)(bp + itn + 32 + 8 * rg);

    // ---- PV half 1 ----
    __builtin_amdgcn_s_setprio(1);
    #pragma unroll
    for (int gg = 0; gg < 4; gg++) {
      int ch = ((4 + gg) ^ s7) * 8 + hl * 4;
      short4v vf0 = *(const short4v*)(vbuf + l32 * 64 + ch);
      short4v vf1 = *(const short4v*)(vbuf + (32 + l32) * 64 + ch);
      o0 = __builtin_amdgcn_mfma_f32_32x32x8bf16_1k(pf1[gg], vf0, o0, 0, 0, 0);
      o1 = __builtin_amdgcn_mfma_f32_32x32x8bf16_1k(pf1[gg], vf1, o1, 0, 0, 0);
    }
    __builtin_amdgcn_s_setprio(0);
  }
#undef STAGE

  // full k-half denominator for q-row l32 (partner half-lane has the other half)
  float l2 = l_run + __shfl_xor(l_run, 32);

  // combine the two k-halves through LDS (K/V buffers dead after the loop)
  float* sO = (float*)smem;              // 128 q x 64 d fp32 = 32 KB
  float* sL = (float*)(smem + 16384);    // 128 floats

  __syncthreads();
  if (g == 1) {
    #pragma unroll
    for (int r = 0; r < 16; r++) {
      int ql = (r & 3) + 8 * (r >> 2) + 4 * hl;
      sO[(wg * 32 + ql) * 64 + l32]      = o0[r];
      sO[(wg * 32 + ql) * 64 + 32 + l32] = o1[r];
    }
    if (hl == 0) sL[wg * 32 + l32] = l2;
  }
  __syncthreads();
  if (g == 0) {
    float linv = __builtin_amdgcn_rcpf(l2 + sL[wg * 32 + l32]);
    #pragma unroll
    for (int r = 0; r < 16; r++) {
      int ql = (r & 3) + 8 * (r >> 2) + 4 * hl;
      float sc = __shfl(linv, ql);
      size_t base = ((size_t)(b * S_ + q0 + ql) * H_ + h) * D_;
      float a0 = o0[r] + sO[(wg * 32 + ql) * 64 + l32];
      float a1 = o1[r] + sO[(wg * 32 + ql) * 64 + 32 + l32];
      Out[base + l32]      = f2bf(a0 * sc);
      Out[base + 32 + l32] = f2bf(a1 * sc);
    }
  }
}

// ---------------- launch ----------------
extern "C" void kernel_launch(void* const* d_in, const int* in_sizes, int n_in,
                              void* d_out, int out_size, void* d_ws, size_t ws_size,
                              hipStream_t stream) {
  (void)in_sizes; (void)n_in; (void)out_size; (void)ws_size;
  const float* x    = (const float*)d_in[0];
  const float* sins = (const float*)d_in[1];
  const float* ab   = (const float*)d_in[2];
  const float* Wq   = (const float*)d_in[3];
  const float* bq   = (const float*)d_in[4];
  const float* Wk   = (const float*)d_in[5];
  const float* bk   = (const float*)d_in[6];
  const float* Wv   = (const float*)d_in[7];
  const float* bv   = (const float*)d_in[8];
  const float* Wo   = (const float*)d_in[9];
  float* out = (float*)d_out;
  char* ws = (char*)d_ws;

  unsigned short* xb  = (unsigned short*)(ws);                       // 8 MB
  unsigned short* Wqt = (unsigned short*)(ws + ((size_t) 8 << 20));  // 2 MB each
  unsigned short* Wkt = (unsigned short*)(ws + ((size_t)10 << 20));
  unsigned short* Wvt = (unsigned short*)(ws + ((size_t)12 << 20));
  unsigned short* Wot = (unsigned short*)(ws + ((size_t)14 << 20));
  unsigned short* Qb  = (unsigned short*)(ws + ((size_t)16 << 20));  // 8 MB
  unsigned short* Kb  = (unsigned short*)(ws + ((size_t)24 << 20));  // 8 MB
  unsigned short* Vtb = (unsigned short*)(ws + ((size_t)32 << 20));  // 8 MB, [b][h][d][s]
  unsigned short* Ab  = (unsigned short*)(ws + ((size_t)40 << 20));  // 8 MB

  const float c1 = 0.125f * 1.44269504088896f;  // 1/sqrt(D) * log2(e), folded into Q

  cast_bf16<<<dim3((M_ * HID_) / (256 * 4)), dim3(256), 0, stream>>>(x, xb);
  transW<<<dim3(32, 32, 4), dim3(32, 8), 0, stream>>>(Wq, Wk, Wv, Wo, Wqt, Wkt, Wvt, Wot);
  gemm_bt<0><<<dim3(8, 32, 3), dim3(256), 0, stream>>>(xb, Wqt, Wkt, Wvt, bq, bk, bv,
                                                       Qb, Kb, Vtb, sins, c1);
  attn<<<dim3(S_ / 128, H_, B_), dim3(512), 0, stream>>>(Qb, Kb, Vtb, ab, Ab);
  gemm_bt64<<<dim3(HID_ / 64, M_ / 128), dim3(256), 0, stream>>>(Ab, Wot, out);
}

// Round 15
// 245.253 us; speedup vs baseline: 1.0757x; 1.0496x over previous
//
#include <hip/hip_runtime.h>
#include <math.h>

#define B_   2
#define S_   2048
#define HID_ 1024
#define D_   64
#define H_   16
#define ROT_ 32
#define M_   (B_*S_)

typedef __attribute__((ext_vector_type(4))) short  short4v;
typedef __attribute__((ext_vector_type(8))) short  short8;
typedef __attribute__((ext_vector_type(4))) float  floatx4;
typedef __attribute__((ext_vector_type(16))) float floatx16;
typedef __attribute__((ext_vector_type(2))) unsigned int uint2v;

__device__ __forceinline__ unsigned short f2bf(float f) {
  unsigned int x = __builtin_bit_cast(unsigned int, f);
  x += 0x7fffu + ((x >> 16) & 1u);   // RNE; inputs finite
  return (unsigned short)(x >> 16);
}
__device__ __forceinline__ unsigned int cvt_pk_bf16(float lo, float hi) {
  unsigned int r;
  asm("v_cvt_pk_bf16_f32 %0, %1, %2" : "=v"(r) : "v"(lo), "v"(hi));
  return r;
}
// async global->LDS, 16B per lane; lds dest = wave-uniform base + lane*16
__device__ __forceinline__ void gload_lds16(const unsigned short* g, unsigned short* l) {
  __builtin_amdgcn_global_load_lds(
      (const __attribute__((address_space(1))) unsigned int*)g,
      (__attribute__((address_space(3))) unsigned int*)l, 16, 0, 0);
}

// ---------------- cast x (fp32 -> bf16) ----------------
__global__ void cast_bf16(const float* __restrict__ in, unsigned short* __restrict__ out) {
  int i = (blockIdx.x * 256 + threadIdx.x) * 4;
  floatx4 v = *(const floatx4*)(in + i);
  unsigned short o[4];
  o[0] = f2bf(v[0]); o[1] = f2bf(v[1]); o[2] = f2bf(v[2]); o[3] = f2bf(v[3]);
  *(unsigned long long*)(out + i) = *(unsigned long long*)o;
}

// ------------- transpose + cast weights: T[n][k] = bf16(W[k][n]) -------------
__global__ void transW(const float* __restrict__ W0, const float* __restrict__ W1,
                       const float* __restrict__ W2, const float* __restrict__ W3,
                       unsigned short* __restrict__ T0, unsigned short* __restrict__ T1,
                       unsigned short* __restrict__ T2, unsigned short* __restrict__ T3) {
  const float* W; unsigned short* T;
  int z = blockIdx.z;
  if (z == 0)      { W = W0; T = T0; }
  else if (z == 1) { W = W1; T = T1; }
  else if (z == 2) { W = W2; T = T2; }
  else             { W = W3; T = T3; }
  __shared__ float tile[32][33];
  int bx = blockIdx.x * 32, by = blockIdx.y * 32;
  int tx = threadIdx.x, ty = threadIdx.y;
  #pragma unroll
  for (int j = 0; j < 4; j++)
    tile[ty + j*8][tx] = W[(size_t)(by + ty + j*8) * HID_ + bx + tx];
  __syncthreads();
  #pragma unroll
  for (int j = 0; j < 4; j++)
    T[(size_t)(bx + ty + j*8) * HID_ + by + tx] = f2bf(tile[tx][ty + j*8]);
}

// ---------------- GEMM: C[M,N] = A[M,K] @ Bt[N,K]^T (+bias) ----------------
// R8 (T4): 3-buffer LDS, ONE raw s_barrier per K-step, counted vmcnt(4).
// R12/R14 (T1-chunked, measured null but harmless): XCD-chunked block remap.
template <int MODE>
__global__ __launch_bounds__(256) void gemm_bt(
    const unsigned short* __restrict__ A,
    const unsigned short* __restrict__ Bt0, const unsigned short* __restrict__ Bt1,
    const unsigned short* __restrict__ Bt2,
    const float* __restrict__ bias0, const float* __restrict__ bias1,
    const float* __restrict__ bias2,
    void* __restrict__ out0, void* __restrict__ out1, void* __restrict__ out2,
    const float* __restrict__ sins, float sc0)
{
  // XCD-chunked remap of the 768-block grid (x=8 n-tiles, y=32 m-tiles, z=3)
  int wg = blockIdx.x + (blockIdx.y << 3) + (blockIdx.z << 8);
  int work = (wg & 7) * 96 + (wg >> 3);
  int zz = work >> 8;
  int rem = work & 255;
  int ty_ = rem >> 3, tx_ = rem & 7;

  const unsigned short* Bt; const float* bias; void* Out; float sc;
  if (zz == 0)      { Bt = Bt0; bias = bias0; Out = out0; sc = sc0; }
  else if (zz == 1) { Bt = Bt1; bias = bias1; Out = out1; sc = 1.f; }
  else              { Bt = Bt2; bias = bias2; Out = out2; sc = 1.f; }
  const int K = HID_, N = HID_;
  int m0 = ty_ * 128, n0 = tx_ * 128;
  __shared__ alignas(16) unsigned short sA[3][128 * 32];
  __shared__ alignas(16) unsigned short sB[3][128 * 32];
  int t = threadIdx.x;
  int lane = t & 63, wave = t >> 6;
  int quad = lane >> 4, l16 = lane & 15;
  int wr = wave >> 1, wc = wave & 1;

  int srow = (lane >> 2), scol = (lane & 3) * 8;
  const unsigned short* gA0 = A  + (size_t)(m0 + wave*32 +  0 + srow) * K + scol;
  const unsigned short* gA1 = A  + (size_t)(m0 + wave*32 + 16 + srow) * K + scol;
  const unsigned short* gB0 = Bt + (size_t)(n0 + wave*32 +  0 + srow) * K + scol;
  const unsigned short* gB1 = Bt + (size_t)(n0 + wave*32 + 16 + srow) * K + scol;

#define GSTAGE(bi, k0) do { \
    gload_lds16(gA0 + (k0), sA[bi] + (wave*32 +  0) * 32); \
    gload_lds16(gA1 + (k0), sA[bi] + (wave*32 + 16) * 32); \
    gload_lds16(gB0 + (k0), sB[bi] + (wave*32 +  0) * 32); \
    gload_lds16(gB1 + (k0), sB[bi] + (wave*32 + 16) * 32); \
  } while (0)

  floatx4 acc[4][4];
  #pragma unroll
  for (int i = 0; i < 4; i++)
    #pragma unroll
    for (int j = 0; j < 4; j++)
      acc[i][j] = (floatx4){0.f, 0.f, 0.f, 0.f};

  const int NK = K / 32;
  GSTAGE(0, 0);
  GSTAGE(1, 32);
  for (int ks = 0; ks < NK; ks++) {
    int cur = ks % 3;
    if (ks + 1 < NK) asm volatile("s_waitcnt vmcnt(4)" ::: "memory");
    else             asm volatile("s_waitcnt vmcnt(0)" ::: "memory");
    __builtin_amdgcn_s_barrier();
    __builtin_amdgcn_sched_barrier(0);
    if (ks + 2 < NK) GSTAGE((ks + 2) % 3, (ks + 2) * 32);

    short8 af[4], bf[4];
    #pragma unroll
    for (int i = 0; i < 4; i++) {
      af[i] = *(const short8*)(sA[cur] + (wr * 64 + i * 16 + l16) * 32 + quad * 8);
      bf[i] = *(const short8*)(sB[cur] + (wc * 64 + i * 16 + l16) * 32 + quad * 8);
    }
    #pragma unroll
    for (int i = 0; i < 4; i++)
      #pragma unroll
      for (int j = 0; j < 4; j++)
        acc[i][j] = __builtin_amdgcn_mfma_f32_16x16x32_bf16(af[i], bf[j], acc[i][j], 0, 0, 0);
  }
#undef GSTAGE

  // Epilogue. C/D layout: col = lane&15, row = quad*4 + reg.
  #pragma unroll
  for (int i = 0; i < 4; i++) {
    int mbase = m0 + wr * 64 + i * 16 + quad * 4;
    #pragma unroll
    for (int j = 0; j < 4; j++) {
      int n = n0 + wc * 64 + j * 16 + l16;
      float bv = bias ? bias[n] : 0.f;
      if (MODE == 1) {
        #pragma unroll
        for (int r = 0; r < 4; r++)
          ((float*)Out)[(size_t)(mbase + r) * N + n] = acc[i][j][r] + bv;
      } else if (zz == 2) {
        // V: write transposed Vt[((b*16+h)*64+dd)*2048 + s], 4 consecutive s packed
        int bb = mbase >> 11, ss = mbase & 2047;
        int hh = n >> 6, dd = n & 63;
        unsigned short pk[4];
        #pragma unroll
        for (int r = 0; r < 4; r++) pk[r] = f2bf(acc[i][j][r] + bv);
        *(unsigned long long*)((unsigned short*)Out +
            (((size_t)(bb * H_ + hh) * D_ + dd) * S_ + ss)) = *(unsigned long long*)pk;
      } else if (j < 2) {
        // rope columns: head-dim index jh = j*16 + l16 < 32 (wave-uniform branch)
        int jh = j * 16 + l16;
        #pragma unroll
        for (int r = 0; r < 4; r++) {
          int row = mbase + r, bb = row >> 11, ss = row & 2047;
          float sn = sins[((size_t)(bb * 2 + 0) * S_ + ss) * ROT_ + jh];
          float cs = sins[((size_t)(bb * 2 + 1) * S_ + ss) * ROT_ + jh];
          float f = (jh & 1) ? (cs + sn) : (cs - sn);
          ((unsigned short*)Out)[(size_t)row * N + n] = f2bf((acc[i][j][r] + bv) * f * sc);
        }
      } else {
        #pragma unroll
        for (int r = 0; r < 4; r++)
          ((unsigned short*)Out)[(size_t)(mbase + r) * N + n] = f2bf((acc[i][j][r] + bv) * sc);
      }
    }
  }
}

// ---- final projection GEMM: 128(M)x64(N) tile, fp32 out, T4 3-buffer ----
__global__ __launch_bounds__(256) void gemm_bt64(
    const unsigned short* __restrict__ A, const unsigned short* __restrict__ Bt,
    float* __restrict__ Out)
{
  const int K = HID_, N = HID_;
  int wg = blockIdx.x + (blockIdx.y << 4);       // x=16 n-tiles, y=32 m-tiles
  int work = (wg & 7) * 64 + (wg >> 3);
  int m0 = (work >> 4) * 128, n0 = (work & 15) * 64;
  __shared__ alignas(16) unsigned short sA[3][128 * 32];
  __shared__ alignas(16) unsigned short sB[3][64 * 32];
  int t = threadIdx.x;
  int lane = t & 63, wave = t >> 6;
  int quad = lane >> 4, l16 = lane & 15;
  int wr = wave >> 1, wc = wave & 1;

  int srow = lane >> 2, scol = (lane & 3) * 8;
  const unsigned short* gA0 = A  + (size_t)(m0 + wave*32 +  0 + srow) * K + scol;
  const unsigned short* gA1 = A  + (size_t)(m0 + wave*32 + 16 + srow) * K + scol;
  const unsigned short* gB0 = Bt + (size_t)(n0 + wave*16 + srow) * K + scol;

#define GSTAGE(bi, k0) do { \
    gload_lds16(gA0 + (k0), sA[bi] + (wave*32 +  0) * 32); \
    gload_lds16(gA1 + (k0), sA[bi] + (wave*32 + 16) * 32); \
    gload_lds16(gB0 + (k0), sB[bi] + (wave*16) * 32); \
  } while (0)

  floatx4 acc[4][2];
  #pragma unroll
  for (int i = 0; i < 4; i++)
    #pragma unroll
    for (int j = 0; j < 2; j++)
      acc[i][j] = (floatx4){0.f, 0.f, 0.f, 0.f};

  const int NK = K / 32;
  GSTAGE(0, 0);
  GSTAGE(1, 32);
  for (int ks = 0; ks < NK; ks++) {
    int cur = ks % 3;
    if (ks + 1 < NK) asm volatile("s_waitcnt vmcnt(3)" ::: "memory");
    else             asm volatile("s_waitcnt vmcnt(0)" ::: "memory");
    __builtin_amdgcn_s_barrier();
    __builtin_amdgcn_sched_barrier(0);
    if (ks + 2 < NK) GSTAGE((ks + 2) % 3, (ks + 2) * 32);

    short8 af[4], bf[2];
    #pragma unroll
    for (int i = 0; i < 4; i++)
      af[i] = *(const short8*)(sA[cur] + (wr * 64 + i * 16 + l16) * 32 + quad * 8);
    #pragma unroll
    for (int j = 0; j < 2; j++)
      bf[j] = *(const short8*)(sB[cur] + (wc * 32 + j * 16 + l16) * 32 + quad * 8);
    #pragma unroll
    for (int i = 0; i < 4; i++)
      #pragma unroll
      for (int j = 0; j < 2; j++)
        acc[i][j] = __builtin_amdgcn_mfma_f32_16x16x32_bf16(af[i], bf[j], acc[i][j], 0, 0, 0);
  }
#undef GSTAGE

  #pragma unroll
  for (int i = 0; i < 4; i++) {
    int mbase = m0 + wr * 64 + i * 16 + quad * 4;
    #pragma unroll
    for (int j = 0; j < 2; j++) {
      int n = n0 + wc * 32 + j * 16 + l16;
      #pragma unroll
      for (int r = 0; r < 4; r++)
        Out[(size_t)(mbase + r) * N + n] = acc[i][j][r];
    }
  }
}

// ---------------- flash attention: NO split-K, 4-wave blocks, 2 blocks/CU ----
// R14 analysis: attn's 7400cyc/tile >> ~700cyc issue-sum; every ~99us variant
// coupled ALL resident waves with one block-wide barrier (8-wave blocks).
// R15 mechanism test: decouple barrier groups at CONSTANT occupancy — 4-wave
// blocks (each wave: 32 q-rows x all 2048 keys, 32 tiles), one K/V stream per
// block, LDS 64KB quad-buffered -> 2 INDEPENDENT blocks/CU (8 waves/CU same
// as R8, but two unsynchronized barrier groups whose stalls can interleave).
// 512 blocks all resident (one round). Split-K combine epilogue deleted.
// Loop body = R8's proven structure (same STAGE shape, same vmcnt(16) ledger:
// prologue 4+8+4+4=20 outstanding, top-wait completes exactly STAGE(it)).
__global__ __launch_bounds__(256, 2) void attn(
    const unsigned short* __restrict__ Q, const unsigned short* __restrict__ Kb,
    const unsigned short* __restrict__ Vt, const float* __restrict__ bias,
    unsigned short* __restrict__ Out)
{
  int b = blockIdx.z, h = blockIdx.y;
  int t = threadIdx.x;
  int lane = t & 63, wave = t >> 6;
  int l32 = lane & 31, hl = lane >> 5;
  int s7 = l32 & 7;
  int q0 = blockIdx.x * 128 + wave * 32;
  const int RS = H_ * D_;
  const int NT = S_ / 64;   // 32 tiles of 64 keys (full sequence per wave)

  // LDS (shorts): K buf[i] at i*4096, V buf[i] at 16384+i*4096 (4 bufs, 64 KB)
  __shared__ alignas(16) unsigned short smem[32768];

  const unsigned short* Qbase = Q + ((size_t)(b * S_) * H_ + h) * D_;
  const unsigned short* Kbase = Kb + ((size_t)(b * S_) * H_ + h) * D_;
  const unsigned short* Vbase = Vt + ((size_t)(b * H_) + h) * D_ * S_;

  // Q B-frags (n=q=lane&31, k=d=16s+8hl+j), fixed for whole kernel
  short8 qf[4];
  {
    const unsigned short* qp = Qbase + (size_t)(q0 + l32) * RS + 8 * hl;
    qf[0] = *(const short8*)(qp);
    qf[1] = *(const short8*)(qp + 16);
    qf[2] = *(const short8*)(qp + 32);
    qf[3] = *(const short8*)(qp + 48);
  }

  // staging: thread t covers 16B chunk of row (t>>3) and row+32; src pre-swizzled
  int row0 = t >> 3;                  // 0..31
  int csw  = (t & 7) ^ (row0 & 7);    // swizzled source chunk (row&7 same for row0+32)
  const unsigned short* gK0 = Kbase + (size_t)(row0)      * RS + csw * 8;
  const unsigned short* gK1 = Kbase + (size_t)(row0 + 32) * RS + csw * 8;
  const unsigned short* gV0 = Vbase + (size_t)(row0)      * S_ + csw * 8;
  const unsigned short* gV1 = Vbase + (size_t)(row0 + 32) * S_ + csw * 8;

  const float* bp = bias + (size_t)b * S_ * S_ + (size_t)(q0 + l32) * S_ + 4 * hl;

#define STAGE(bi, tk) do { \
    unsigned short* kb_ = smem + (bi) * 4096; \
    unsigned short* vb_ = smem + 16384 + (bi) * 4096; \
    size_t ko_ = (size_t)(tk) * 64 * RS; int vo_ = (tk) * 64; \
    gload_lds16(gK0 + ko_, kb_ + t * 8); \
    gload_lds16(gK1 + ko_, kb_ + (256 + t) * 8); \
    gload_lds16(gV0 + vo_, vb_ + t * 8); \
    gload_lds16(gV1 + vo_, vb_ + (256 + t) * 8); \
  } while (0)

  float l_run = 0.f;
  floatx16 o0, o1;
  #pragma unroll
  for (int r = 0; r < 16; r++) { o0[r] = 0.f; o1[r] = 0.f; }

  // prologue (VMEM order matters for the counted waits):
  // stage(0) 4, bias(0) 8, stage(1) 4, stage(2) 4  -> 20 in flight
  STAGE(0, 0);
  floatx4 b0[4], b1[4];
  #pragma unroll
  for (int rg = 0; rg < 4; rg++) {
    b0[rg] = *(const floatx4*)(bp + 8 * rg);
    b1[rg] = *(const floatx4*)(bp + 32 + 8 * rg);
  }
  STAGE(1, 1);
  STAGE(2, 2);

  for (int it = 0; it < NT; ++it) {
    int cur = it & 3;
    // counted wait: stage(cur) complete, newer stages + bias stay in flight
    asm volatile("s_waitcnt vmcnt(16)" ::: "memory");
    __builtin_amdgcn_s_barrier();
    __builtin_amdgcn_sched_barrier(0);
    if (it < NT - 3) STAGE((it + 3) & 3, it + 3);

    const unsigned short* kbuf = smem + cur * 4096;
    const unsigned short* vbuf = smem + 16384 + cur * 4096;
    int itn = ((it + 1) & (NT - 1)) * 64;

    // ---- QK^T half 0: S^T rows k=0..31 (D[m=k][n=q]) ----
    floatx16 st;
    #pragma unroll
    for (int r = 0; r < 16; r++) st[r] = 0.f;
    __builtin_amdgcn_s_setprio(1);
    #pragma unroll
    for (int ks = 0; ks < 4; ks++) {
      short8 kf = *(const short8*)(kbuf + l32 * 64 + (((2 * ks + hl) ^ s7) * 8));
      st = __builtin_amdgcn_mfma_f32_32x32x16_bf16(kf, qf[ks], st, 0, 0, 0);
    }
    __builtin_amdgcn_s_setprio(0);

    // ---- softmax half 0 -> pf0; refill b0 for next tile ----
    short4v pf0[4];
    #pragma unroll
    for (int rg = 0; rg < 4; rg++) {
      float p0 = __builtin_amdgcn_exp2f(st[rg * 4 + 0]);
      float p1 = __builtin_amdgcn_exp2f(st[rg * 4 + 1]);
      float p2 = __builtin_amdgcn_exp2f(st[rg * 4 + 2]);
      float p3 = __builtin_amdgcn_exp2f(st[rg * 4 + 3]);
      l_run += (p0 + p1) + (p2 + p3);
      uint2v u;
      u[0] = cvt_pk_bf16(p0 * b0[rg][0], p1 * b0[rg][1]);
      u[1] = cvt_pk_bf16(p2 * b0[rg][2], p3 * b0[rg][3]);
      pf0[rg] = __builtin_bit_cast(short4v, u);
    }
    #pragma unroll
    for (int rg = 0; rg < 4; rg++)
      b0[rg] = *(const floatx4*)(bp + itn + 8 * rg);

    // ---- QK^T half 1 (st registers recycled) ----
    floatx16 st1;
    #pragma unroll
    for (int r = 0; r < 16; r++) st1[r] = 0.f;
    __builtin_amdgcn_s_setprio(1);
    #pragma unroll
    for (int ks = 0; ks < 4; ks++) {
      short8 kf = *(const short8*)(kbuf + (32 + l32) * 64 + (((2 * ks + hl) ^ s7) * 8));
      st1 = __builtin_amdgcn_mfma_f32_32x32x16_bf16(kf, qf[ks], st1, 0, 0, 0);
    }
    // ---- PV half 0 ----
    #pragma unroll
    for (int gg = 0; gg < 4; gg++) {
      int ch = (gg ^ s7) * 8 + hl * 4;
      short4v vf0 = *(const short4v*)(vbuf + l32 * 64 + ch);
      short4v vf1 = *(const short4v*)(vbuf + (32 + l32) * 64 + ch);
      o0 = __builtin_amdgcn_mfma_f32_32x32x8bf16_1k(pf0[gg], vf0, o0, 0, 0, 0);
      o1 = __builtin_amdgcn_mfma_f32_32x32x8bf16_1k(pf0[gg], vf1, o1, 0, 0, 0);
    }
    __builtin_amdgcn_s_setprio(0);

    // ---- softmax half 1 -> pf1; refill b1 ----
    short4v pf1[4];
    #pragma unroll
    for (int rg = 0; rg < 4; rg++) {
      float p0 = __builtin_amdgcn_exp2f(st1[rg * 4 + 0]);
      float p1 = __builtin_amdgcn_exp2f(st1[rg * 4 + 1]);
      float p2 = __builtin_amdgcn_exp2f(st1[rg * 4 + 2]);
      float p3 = __builtin_amdgcn_exp2f(st1[rg * 4 + 3]);
      l_run += (p0 + p1) + (p2 + p3);
      uint2v u;
      u[0] = cvt_pk_bf16(p0 * b1[rg][0], p1 * b1[rg][1]);
      u[1] = cvt_pk_bf16(p2 * b1[rg][2], p3 * b1[rg][3]);
      pf1[rg] = __builtin_bit_cast(short4v, u);
    }
    #pragma unroll
    for (int rg = 0; rg < 4; rg++)
      b1[rg] = *(const floatx4*)(bp + itn + 32 + 8 * rg);

    // ---- PV half 1 ----
    __builtin_amdgcn_s_setprio(1);
    #pragma unroll
    for (int gg = 0; gg < 4; gg++) {
      int ch = ((4 + gg) ^ s7) * 8 + hl * 4;
      short4v vf0 = *(const short4v*)(vbuf + l32 * 64 + ch);
      short4v vf1 = *(const short4v*)(vbuf + (32 + l32) * 64 + ch);
      o0 = __builtin_amdgcn_mfma_f32_32x32x8bf16_1k(pf1[gg], vf0, o0, 0, 0, 0);
      o1 = __builtin_amdgcn_mfma_f32_32x32x8bf16_1k(pf1[gg], vf1, o1, 0, 0, 0);
    }
    __builtin_amdgcn_s_setprio(0);
  }
#undef STAGE

  // epilogue: direct write (no split-K combine). Partner half-lane holds the
  // other 16 of each 32-k block -> full denominator via one shfl_xor.
  float linv = __builtin_amdgcn_rcpf(l_run + __shfl_xor(l_run, 32));
  #pragma unroll
  for (int r = 0; r < 16; r++) {
    int ql = (r & 3) + 8 * (r >> 2) + 4 * hl;
    float sc = __shfl(linv, ql);
    size_t base = ((size_t)(b * S_ + q0 + ql) * H_ + h) * D_;
    Out[base + l32]      = f2bf(o0[r] * sc);
    Out[base + 32 + l32] = f2bf(o1[r] * sc);
  }
}

// ---------------- launch ----------------
extern "C" void kernel_launch(void* const* d_in, const int* in_sizes, int n_in,
                              void* d_out, int out_size, void* d_ws, size_t ws_size,
                              hipStream_t stream) {
  (void)in_sizes; (void)n_in; (void)out_size; (void)ws_size;
  const float* x    = (const float*)d_in[0];
  const float* sins = (const float*)d_in[1];
  const float* ab   = (const float*)d_in[2];
  const float* Wq   = (const float*)d_in[3];
  const float* bq   = (const float*)d_in[4];
  const float* Wk   = (const float*)d_in[5];
  const float* bk   = (const float*)d_in[6];
  const float* Wv   = (const float*)d_in[7];
  const float* bv   = (const float*)d_in[8];
  const float* Wo   = (const float*)d_in[9];
  float* out = (float*)d_out;
  char* ws = (char*)d_ws;

  unsigned short* xb  = (unsigned short*)(ws);                       // 8 MB
  unsigned short* Wqt = (unsigned short*)(ws + ((size_t) 8 << 20));  // 2 MB each
  unsigned short* Wkt = (unsigned short*)(ws + ((size_t)10 << 20));
  unsigned short* Wvt = (unsigned short*)(ws + ((size_t)12 << 20));
  unsigned short* Wot = (unsigned short*)(ws + ((size_t)14 << 20));
  unsigned short* Qb  = (unsigned short*)(ws + ((size_t)16 << 20));  // 8 MB
  unsigned short* Kb  = (unsigned short*)(ws + ((size_t)24 << 20));  // 8 MB
  unsigned short* Vtb = (unsigned short*)(ws + ((size_t)32 << 20));  // 8 MB, [b][h][d][s]
  unsigned short* Ab  = (unsigned short*)(ws + ((size_t)40 << 20));  // 8 MB

  const float c1 = 0.125f * 1.44269504088896f;  // 1/sqrt(D) * log2(e), folded into Q

  cast_bf16<<<dim3((M_ * HID_) / (256 * 4)), dim3(256), 0, stream>>>(x, xb);
  transW<<<dim3(32, 32, 4), dim3(32, 8), 0, stream>>>(Wq, Wk, Wv, Wo, Wqt, Wkt, Wvt, Wot);
  gemm_bt<0><<<dim3(8, 32, 3), dim3(256), 0, stream>>>(xb, Wqt, Wkt, Wvt, bq, bk, bv,
                                                       Qb, Kb, Vtb, sins, c1);
  attn<<<dim3(S_ / 128, H_, B_), dim3(256), 0, stream>>>(Qb, Kb, Vtb, ab, Ab);
  gemm_bt64<<<dim3(HID_ / 64, M_ / 128), dim3(256), 0, stream>>>(Ab, Wot, out);
}